// Round 8
// baseline (334.224 us; speedup 1.0000x reference)
//
#include <hip/hip_runtime.h>

typedef _Float16 f16x8 __attribute__((ext_vector_type(8)));
typedef float f32x4 __attribute__((ext_vector_type(4)));

static constexpr int S = 4;
static constexpr int NATOMS = 32768;
static constexpr int FIN = 512;
static constexpr int H = 256;
static constexpr int WM = 16;    // atoms per wave
static constexpr int HSTR = 264; // private h plane: 256 cols + 8 pad fp16 (528B rows)

// ---- weight packing: fp32 [S][K][H] -> fragment-major fp16 (1-term) ----
// frag = 64 lanes x 8 fp16. Element (lane,j): k = kt*32+(lane>>4)*8+j ; n = ntile*16+(lane&15)
__global__ void pack_w(const float* __restrict__ W, _Float16* __restrict__ dst, int KT) {
    int idx = blockIdx.x * 256 + threadIdx.x;
    int j = idx & 7;
    int lane = (idx >> 3) & 63;
    int rest = idx >> 9;
    int kt = rest % KT;
    int t2 = rest / KT;            // s*16 + ntile
    int K = KT * 32;
    int k = kt * 32 + (lane >> 4) * 8 + j;
    int n = (t2 & 15) * 16 + (lane & 15);
    int s = t2 >> 4;
    dst[(((size_t)t2 * KT + kt) * 64 + lane) * 8 + j] = (_Float16)W[((size_t)s * K + k) * H + n];
}

__global__ void init_out(float* __restrict__ out, const float* __restrict__ shift, int n) {
    int i = blockIdx.x * 256 + threadIdx.x;
    if (i < n) out[i] = shift[0];
}

__device__ __forceinline__ void wave_lds_fence() {
    // intra-wave LDS write->read ordering; no s_barrier needed (private region)
    asm volatile("s_waitcnt lgkmcnt(0)" ::: "memory");
    __builtin_amdgcn_sched_barrier(0);
}

__global__ __launch_bounds__(256, 3) void fused_mlp(
    const float* __restrict__ X, const int* __restrict__ ids,
    const _Float16* __restrict__ W1p, const _Float16* __restrict__ W2p,
    const _Float16* __restrict__ W3p,
    const float* __restrict__ b1, const float* __restrict__ b2,
    const float* __restrict__ b3,
    const float* __restrict__ W4, const float* __restrict__ b4,
    float* __restrict__ out)
{
    // Per-wave PRIVATE h plane: waves never exchange data -> zero barriers.
    __shared__ _Float16 smem[4 * WM * HSTR];

    const int s = blockIdx.y;
    const int tile = blockIdx.x;   // 512 tiles of 64 atoms; wave owns 16
    const int tid = threadIdx.x;
    const int w = tid >> 6;
    const int lane = tid & 63;
    const int g = lane >> 4;
    const int mh = lane & 15;

    _Float16* hw = smem + w * (WM * HSTR);
    const int atom0 = tile * 64 + w * WM;
    const float* Xw = X + ((size_t)s * NATOMS + atom0) * FIN;

    f32x4 acc[16];
#pragma unroll
    for (int i = 0; i < 16; ++i) acc[i] = f32x4{0.f, 0.f, 0.f, 0.f};

    // ---------------- layer 1: [16x512] @ [512x256], direct-global A ----------------
    {
        const float* pl = Xw + (size_t)mh * FIN + g * 8;
#pragma unroll
        for (int ks = 0; ks < 16; ++ks) {
            f32x4 u = *(const f32x4*)(pl + ks * 32);
            f32x4 v = *(const f32x4*)(pl + ks * 32 + 4);
            f16x8 a;
#pragma unroll
            for (int j = 0; j < 4; ++j) {
                a[j] = (_Float16)u[j];
                a[j + 4] = (_Float16)v[j];
            }
#pragma unroll
            for (int nt = 0; nt < 16; ++nt) {
                const _Float16* fp = W1p +
                    ((((size_t)(s * 16 + nt)) * 16 + ks) << 9) + lane * 8;
                f16x8 b = *(const f16x8*)fp;
                acc[nt] = __builtin_amdgcn_mfma_f32_16x16x32_f16(a, b, acc[nt], 0, 0, 0);
            }
        }
    }

    // bias + silu -> private h plane (rows 0..15 = wave's atoms)
#pragma unroll
    for (int nt = 0; nt < 16; ++nt) {
        float bv = b1[s * H + nt * 16 + mh];
#pragma unroll
        for (int r = 0; r < 4; ++r) {
            float v = acc[nt][r] + bv;
            v = __fdividef(v, 1.f + __expf(-v));
            hw[(g * 4 + r) * HSTR + nt * 16 + mh] = (_Float16)v;
            acc[nt][r] = 0.f;
        }
    }
    wave_lds_fence();

    // ---------------- layers 2 and 3: [16x256] @ [256x256] ----------------
    for (int l = 0; l < 2; ++l) {
        const _Float16* Wp = l ? W3p : W2p;
        const float* bp = l ? nullptr : b2;  // l==1 epilogue handled in L4 block
#pragma unroll
        for (int ks = 0; ks < 8; ++ks) {
            f16x8 a = *(const f16x8*)(hw + mh * HSTR + ks * 32 + g * 8);
#pragma unroll
            for (int nt = 0; nt < 16; ++nt) {
                const _Float16* fp = Wp +
                    ((((size_t)(s * 16 + nt)) * 8 + ks) << 9) + lane * 8;
                f16x8 b = *(const f16x8*)fp;
                acc[nt] = __builtin_amdgcn_mfma_f32_16x16x32_f16(a, b, acc[nt], 0, 0, 0);
            }
        }
        if (l == 0) {
            wave_lds_fence();  // all reads of h1 done (in-order LDS pipe) before overwrite
#pragma unroll
            for (int nt = 0; nt < 16; ++nt) {
                float bv = bp[s * H + nt * 16 + mh];
#pragma unroll
                for (int r = 0; r < 4; ++r) {
                    float v = acc[nt][r] + bv;
                    v = __fdividef(v, 1.f + __expf(-v));
                    hw[(g * 4 + r) * HSTR + nt * 16 + mh] = (_Float16)v;
                    acc[nt][r] = 0.f;
                }
            }
            wave_lds_fence();
        }
    }

    // ---------------- layer 3 activation + layer 4 dot + reduce ----------------
    {
        float b4v = b4[s];
#pragma unroll
        for (int r = 0; r < 4; ++r) {
            float v = 0.f;
#pragma unroll
            for (int nt = 0; nt < 16; ++nt) {
                float h = acc[nt][r] + b3[s * H + nt * 16 + mh];
                h = __fdividef(h, 1.f + __expf(-h));
                v += h * W4[s * H + nt * 16 + mh];
            }
            // sum over the 16 mh-lanes (columns); atom = g*4 + r
            v += __shfl_xor(v, 1);
            v += __shfl_xor(v, 2);
            v += __shfl_xor(v, 4);
            v += __shfl_xor(v, 8);
            if (mh == r) {
                int id = ids[(size_t)s * NATOMS + atom0 + g * 4 + r];
                atomicAdd(&out[id], v + b4v);
            }
        }
    }
}

extern "C" void kernel_launch(void* const* d_in, const int* in_sizes, int n_in,
                              void* d_out, int out_size, void* d_ws, size_t ws_size,
                              hipStream_t stream) {
    const float* X   = (const float*)d_in[0];
    const int*   ids = (const int*)d_in[1];
    const float* W1  = (const float*)d_in[2];
    const float* b1  = (const float*)d_in[3];
    const float* W2  = (const float*)d_in[4];
    const float* b2  = (const float*)d_in[5];
    const float* W3  = (const float*)d_in[6];
    const float* b3  = (const float*)d_in[7];
    const float* W4  = (const float*)d_in[8];
    const float* b4  = (const float*)d_in[9];
    const float* shift = (const float*)d_in[10];

    // packed fp16 weights (1-term): W1p 1MB, W2p 512KB, W3p 512KB
    _Float16* W1p = (_Float16*)d_ws;
    _Float16* W2p = W1p + (size_t)S * 16 * 16 * 512;
    _Float16* W3p = W2p + (size_t)S * 16 * 8 * 512;

    pack_w<<<2048, 256, 0, stream>>>(W1, W1p, 16);
    pack_w<<<1024, 256, 0, stream>>>(W2, W2p, 8);
    pack_w<<<1024, 256, 0, stream>>>(W3, W3p, 8);

    init_out<<<(out_size + 255) / 256, 256, 0, stream>>>((float*)d_out, shift, out_size);

    dim3 grid(NATOMS / 64, S);
    fused_mlp<<<grid, 256, 0, stream>>>(X, ids, W1p, W2p, W3p, b1, b2, b3, W4, b4,
                                        (float*)d_out);
}

// Round 9
// 158.016 us; speedup vs baseline: 2.1151x; 2.1151x over previous
//
#include <hip/hip_runtime.h>

typedef _Float16 f16x8 __attribute__((ext_vector_type(8)));
typedef _Float16 f16x4 __attribute__((ext_vector_type(4)));
typedef float f32x4 __attribute__((ext_vector_type(4)));

static constexpr int S = 4;
static constexpr int NATOMS = 32768;
static constexpr int FIN = 512;
static constexpr int H = 256;
static constexpr int BM = 64;    // atoms per block
static constexpr int XSTR = 72;  // fp16/row (144B): 2-way banks, free
static constexpr int HSTR = 264; // h plane: 256 cols + 8 pad fp16 (528B rows, 2-way)

// ---- weight packing: fp32 [S][K][H] -> fragment-major fp16 (1-term) ----
// frag = 64 lanes x 8 fp16. Element (lane,j): k = kt*32+(lane>>4)*8+j ; n = ntile*16+(lane&15)
__global__ void pack_w(const float* __restrict__ W, _Float16* __restrict__ dst, int KT) {
    int idx = blockIdx.x * 256 + threadIdx.x;
    int j = idx & 7;
    int lane = (idx >> 3) & 63;
    int rest = idx >> 9;
    int kt = rest % KT;
    int t2 = rest / KT;            // s*16 + ntile
    int K = KT * 32;
    int k = kt * 32 + (lane >> 4) * 8 + j;
    int n = (t2 & 15) * 16 + (lane & 15);
    int s = t2 >> 4;
    dst[(((size_t)t2 * KT + kt) * 64 + lane) * 8 + j] = (_Float16)W[((size_t)s * K + k) * H + n];
}

__global__ void init_out(float* __restrict__ out, const float* __restrict__ shift, int n) {
    int i = blockIdx.x * 256 + threadIdx.x;
    if (i < n) out[i] = shift[0];
}

__global__ __launch_bounds__(512, 4) void fused_mlp(
    const float* __restrict__ X, const int* __restrict__ ids,
    const _Float16* __restrict__ W1p, const _Float16* __restrict__ W2p,
    const _Float16* __restrict__ W3p,
    const float* __restrict__ b1, const float* __restrict__ b2,
    const float* __restrict__ b3,
    const float* __restrict__ W4, const float* __restrict__ b4,
    float* __restrict__ out)
{
    // union: X fp16 TRIPLE buffer [3][64][72] (27648B) aliased by h fp16 plane
    // [64][264] (33792B). h written only after all layer-1 LDS reads are done.
    __shared__ _Float16 smem[BM * HSTR];
    __shared__ float e_lds[8][BM];

    const int s = blockIdx.y;
    const int tile = blockIdx.x;
    const int tid = threadIdx.x;
    const int w = tid >> 6;        // 0..7: 32-col slice of H (N-split across 8 waves)
    const int lane = tid & 63;
    const int g = lane >> 4;
    const int mh = lane & 15;
    const int srow = tid >> 3;     // staging row (64 rows, 8 threads/row)
    const int cq = tid & 7;        // staging col group (8 floats each)

    const float* Xb = X + (size_t)(s * NATOMS + tile * BM) * FIN;
    _Float16* hb = smem;

    f32x4 acc[4][2];
#pragma unroll
    for (int i = 0; i < 4; ++i)
#pragma unroll
        for (int j = 0; j < 2; ++j)
            acc[i][j] = f32x4{0.f, 0.f, 0.f, 0.f};

    // ---- layer-1 staging: global->reg (f32) -> cvt once -> LDS (f16) ----
    // Thread loads 8 consecutive floats (32B); 8 threads/row cover 256B (coalesced).
    f32x4 ld[3][2];
    auto loadc = [&](int slot, int c) {
        const float* p = Xb + (size_t)srow * FIN + c * 64 + cq * 8;
        ld[slot][0] = *(const f32x4*)(p);
        ld[slot][1] = *(const f32x4*)(p + 4);
    };
    auto storec = [&](int slot, int c) {
        _Float16* xb = smem + (c % 3) * (BM * XSTR);
#pragma unroll
        for (int i = 0; i < 2; ++i) {
            f16x4 v;
#pragma unroll
            for (int j = 0; j < 4; ++j) v[j] = (_Float16)ld[slot][i][j];
            *(f16x4*)(xb + srow * XSTR + cq * 8 + i * 4) = v;
        }
    };
    // A-fragment: ONE ds_read_b128 feeding MFMA directly
    auto l1mfma = [&](int c) {
        const _Float16* xb = smem + (c % 3) * (BM * XSTR);
#pragma unroll
        for (int ks = 0; ks < 2; ++ks) {
            f16x8 a[4];
#pragma unroll
            for (int mt = 0; mt < 4; ++mt)
                a[mt] = *(const f16x8*)(xb + (mt * 16 + mh) * XSTR + (ks * 4 + g) * 8);
            __builtin_amdgcn_s_setprio(1);
#pragma unroll
            for (int nt = 0; nt < 2; ++nt) {
                const _Float16* fp = W1p +
                    ((((size_t)(s * 16 + w * 2 + nt)) * 16 + c * 2 + ks) << 9) + lane * 8;
                f16x8 b = *(const f16x8*)fp;
#pragma unroll
                for (int mt = 0; mt < 4; ++mt)
                    acc[mt][nt] = __builtin_amdgcn_mfma_f32_16x16x32_f16(a[mt], b, acc[mt][nt], 0, 0, 0);
            }
            __builtin_amdgcn_s_setprio(0);
        }
    };

    // ---------------- layer 1: [64x512] @ [512x256] ----------------
    // Reg slots hold chunks ~2 iterations ahead; raw s_barrier waits only
    // lgkmcnt(0) (ds_writes visible) -- global loads stay in flight across it.
    loadc(0, 0);
    loadc(1, 1);
    loadc(2, 2);
    storec(0, 0);
    asm volatile("s_waitcnt lgkmcnt(0)" ::: "memory");
    __builtin_amdgcn_s_barrier();
#pragma unroll
    for (int c = 0; c < 8; ++c) {
        if (c < 7) storec((c + 1) % 3, c + 1);  // slot holds chunk c+1 (loaded iter c-2)
        if (c < 5) loadc(c % 3, c + 3);         // slot's old chunk already in LDS
        l1mfma(c);
        asm volatile("s_waitcnt lgkmcnt(0)" ::: "memory");
        __builtin_amdgcn_s_barrier();
    }
    __syncthreads();  // full drain before h overwrites the X union

    // bias + silu -> h1 (fp16 plane)
    {
        float bv[2];
#pragma unroll
        for (int nt = 0; nt < 2; ++nt) bv[nt] = b1[s * H + w * 32 + nt * 16 + mh];
#pragma unroll
        for (int mt = 0; mt < 4; ++mt)
#pragma unroll
            for (int nt = 0; nt < 2; ++nt)
#pragma unroll
                for (int r = 0; r < 4; ++r) {
                    float v = acc[mt][nt][r] + bv[nt];
                    v = v / (1.f + __expf(-v));
                    hb[(mt * 16 + g * 4 + r) * HSTR + w * 32 + nt * 16 + mh] = (_Float16)v;
                    acc[mt][nt][r] = 0.f;
                }
    }
    __syncthreads();

    // ---------------- layers 2 and 3: [64x256] @ [256x256] ----------------
    for (int l = 0; l < 2; ++l) {
        const _Float16* Wp = l ? W3p : W2p;
#pragma unroll
        for (int ks = 0; ks < 8; ++ks) {
            f16x8 a[4];
#pragma unroll
            for (int mt = 0; mt < 4; ++mt)
                a[mt] = *(const f16x8*)(hb + (mt * 16 + mh) * HSTR + ks * 32 + g * 8);
            __builtin_amdgcn_s_setprio(1);
#pragma unroll
            for (int nt = 0; nt < 2; ++nt) {
                const _Float16* fp = Wp +
                    ((((size_t)(s * 16 + w * 2 + nt)) * 8 + ks) << 9) + lane * 8;
                f16x8 b = *(const f16x8*)fp;
#pragma unroll
                for (int mt = 0; mt < 4; ++mt)
                    acc[mt][nt] = __builtin_amdgcn_mfma_f32_16x16x32_f16(a[mt], b, acc[mt][nt], 0, 0, 0);
            }
            __builtin_amdgcn_s_setprio(0);
        }
        __syncthreads();  // all reads of h done before overwrite
        if (l == 0) {
            float bv[2];
#pragma unroll
            for (int nt = 0; nt < 2; ++nt) bv[nt] = b2[s * H + w * 32 + nt * 16 + mh];
#pragma unroll
            for (int mt = 0; mt < 4; ++mt)
#pragma unroll
                for (int nt = 0; nt < 2; ++nt)
#pragma unroll
                    for (int r = 0; r < 4; ++r) {
                        float v = acc[mt][nt][r] + bv[nt];
                        v = v / (1.f + __expf(-v));
                        hb[(mt * 16 + g * 4 + r) * HSTR + w * 32 + nt * 16 + mh] = (_Float16)v;
                        acc[mt][nt][r] = 0.f;
                    }
            __syncthreads();
        }
    }

    // ---------------- layer 3 activation + layer 4 dot + reduce ----------------
    {
        float bv[2], w4v[2];
#pragma unroll
        for (int nt = 0; nt < 2; ++nt) {
            int col = w * 32 + nt * 16 + mh;
            bv[nt] = b3[s * H + col];
            w4v[nt] = W4[s * H + col];
        }
#pragma unroll
        for (int mt = 0; mt < 4; ++mt)
#pragma unroll
            for (int r = 0; r < 4; ++r) {
                float v = 0.f;
#pragma unroll
                for (int nt = 0; nt < 2; ++nt) {
                    float h = acc[mt][nt][r] + bv[nt];
                    h = h / (1.f + __expf(-h));
                    v += h * w4v[nt];
                }
                v += __shfl_xor(v, 1);
                v += __shfl_xor(v, 2);
                v += __shfl_xor(v, 4);
                v += __shfl_xor(v, 8);
                if (mh == r) e_lds[w][mt * 16 + g * 4 + r] = v;
            }
    }
    __syncthreads();
    if (tid < BM) {
        float e = b4[s];
#pragma unroll
        for (int j = 0; j < 8; ++j) e += e_lds[j][tid];
        int id = ids[s * NATOMS + tile * BM + tid];
        atomicAdd(&out[id], e);
    }
}

extern "C" void kernel_launch(void* const* d_in, const int* in_sizes, int n_in,
                              void* d_out, int out_size, void* d_ws, size_t ws_size,
                              hipStream_t stream) {
    const float* X   = (const float*)d_in[0];
    const int*   ids = (const int*)d_in[1];
    const float* W1  = (const float*)d_in[2];
    const float* b1  = (const float*)d_in[3];
    const float* W2  = (const float*)d_in[4];
    const float* b2  = (const float*)d_in[5];
    const float* W3  = (const float*)d_in[6];
    const float* b3  = (const float*)d_in[7];
    const float* W4  = (const float*)d_in[8];
    const float* b4  = (const float*)d_in[9];
    const float* shift = (const float*)d_in[10];

    // packed fp16 weights (1-term): W1p 1MB, W2p 512KB, W3p 512KB
    _Float16* W1p = (_Float16*)d_ws;
    _Float16* W2p = W1p + (size_t)S * 16 * 16 * 512;
    _Float16* W3p = W2p + (size_t)S * 16 * 8 * 512;

    pack_w<<<2048, 256, 0, stream>>>(W1, W1p, 16);
    pack_w<<<1024, 256, 0, stream>>>(W2, W2p, 8);
    pack_w<<<1024, 256, 0, stream>>>(W3, W3p, 8);

    init_out<<<(out_size + 255) / 256, 256, 0, stream>>>((float*)d_out, shift, out_size);

    dim3 grid(NATOMS / BM, S);
    fused_mlp<<<grid, 512, 0, stream>>>(X, ids, W1p, W2p, W3p, b1, b2, b3, W4, b4,
                                        (float*)d_out);
}